// Round 10
// baseline (478.580 us; speedup 1.0000x reference)
//
#include <hip/hip_runtime.h>
#include <cstdint>

#define D 128
#define P 8
#define L 3

typedef __attribute__((ext_vector_type(8))) _Float16 f16x8;
typedef __attribute__((ext_vector_type(4))) float    f32x4;

// row_ptr[r] = lower_bound(edge_row, r); edge_row is sorted.
__global__ void build_row_ptr(const int* __restrict__ er, int* __restrict__ rp, int n, int e) {
    int r = blockIdx.x * blockDim.x + threadIdx.x;
    if (r > n) return;
    int lo = 0, hi = e;
    while (lo < hi) {
        int mid = (lo + hi) >> 1;
        if (er[mid] < r) lo = mid + 1; else hi = mid;
    }
    rp[r] = lo;
}

// ww = softmax-contracted weights, fp16, MFMA B-fragment layout:
// wwB[l][kt][o][k']  (i = kt*32 + k'); b-frag load is 16B contiguous.
__global__ void build_ww(const float* __restrict__ sp, const float* __restrict__ lw,
                         _Float16* __restrict__ wwB) {
    int idx = blockIdx.x * blockDim.x + threadIdx.x;
    if (idx >= L * D * D) return;
    int l = idx / (D * D);
    int rem = idx - l * D * D;
    int o = rem / D;
    int i = rem - o * D;
    float wv[P];
    float m = -1e30f;
#pragma unroll
    for (int p = 0; p < P; p++) { wv[p] = lw[l * P + p]; m = fmaxf(m, wv[p]); }
    float s = 0.f;
#pragma unroll
    for (int p = 0; p < P; p++) { wv[p] = __expf(wv[p] - m); s += wv[p]; }
    float inv = 1.0f / s;
    const float* spp = sp + ((size_t)(l * D + o) * D + i) * P;
    float acc = 0.f;
#pragma unroll
    for (int p = 0; p < P; p++) acc += spp[p] * wv[p];
    int kt = i >> 5, kp = i & 31;
    wwB[(((l * 4 + kt) * D + o) << 5) + kp] = (_Float16)(acc * inv);
}

// MFMA on a 16x128 fp16 staged tile: 8 output col-tiles split 2-per-wave.
static __device__ __forceinline__ void mfma_store16(const _Float16 (*s_h)[136],
                                                    const _Float16* __restrict__ wwB_l,
                                                    _Float16* __restrict__ y,
                                                    int row0, int n, int tid) {
    const int w = tid >> 6, lane = tid & 63;
    const int quad = lane >> 4, l16 = lane & 15;
    f32x4 acc[2] = {};
#pragma unroll
    for (int kt = 0; kt < 4; kt++) {
        f16x8 af = *(const f16x8*)&s_h[l16][kt * 32 + quad * 8];
#pragma unroll
        for (int c = 0; c < 2; c++) {
            const int ct = w * 2 + c;
            f16x8 bf = *(const f16x8*)&wwB_l[((kt * D + ct * 16 + l16) << 5) + quad * 8];
            acc[c] = __builtin_amdgcn_mfma_f32_16x16x32_f16(af, bf, acc[c], 0, 0, 0);
        }
    }
    // C/D layout: col = lane&15, row = quad*4 + reg (m89-verified)
#pragma unroll
    for (int c = 0; c < 2; c++) {
        const int ct = w * 2 + c;
#pragma unroll
        for (int rg = 0; rg < 4; rg++) {
            int row = row0 + quad * 4 + rg;
            if (row < n) y[row * D + ct * 16 + l16] = (_Float16)acc[c][rg];
        }
    }
}

// Y1 = cast_f16(x) * W0   (x fp32 read directly; cast fused). 16-row tiles.
__global__ __launch_bounds__(256, 8)
void gemm_x32(const float* __restrict__ x, const _Float16* __restrict__ wwB_l,
              _Float16* __restrict__ y, int n) {
    __shared__ _Float16 s_h[16][136];
    const int tid = threadIdx.x;
    const int row0 = blockIdx.x * 16;
    const int c8 = (tid & 15) * 8;
    {
        int r = tid >> 4;
        int row = row0 + r;
        float4 v0 = {}, v1 = {};
        if (row < n) {
            v0 = *(const float4*)&x[row * D + c8];
            v1 = *(const float4*)&x[row * D + c8 + 4];
        }
        f16x8 h;
        h[0] = (_Float16)v0.x; h[1] = (_Float16)v0.y;
        h[2] = (_Float16)v0.z; h[3] = (_Float16)v0.w;
        h[4] = (_Float16)v1.x; h[5] = (_Float16)v1.y;
        h[6] = (_Float16)v1.z; h[7] = (_Float16)v1.w;
        *(f16x8*)&s_h[r][c8] = h;
    }
    __syncthreads();
    mfma_store16(s_h, wwB_l, y, row0, n, tid);
}

// Fused layer, edge-balanced: 16 subgroups split the tile's edge range into
// equal contiguous chunks; row-boundary partials merge via LDS fp32 atomics.
// Then relu+cvt feeds the block MFMA. Block time ~ mean degree, not max.
__global__ __launch_bounds__(256, 8)
void fused_layer(const _Float16* __restrict__ yprev, const int* __restrict__ rp,
                 const int* __restrict__ col, const float* __restrict__ vals,
                 const _Float16* __restrict__ wwB_l, _Float16* __restrict__ ynext, int n) {
    __shared__ float s_acc[16][132];   // fp32 accum, +4 pad (2-way LDS aliasing = free)
    __shared__ int   s_rp[17];
    const int tid = threadIdx.x;
    const int row0 = blockIdx.x * 16;
    if (tid < 17) {
        int r = row0 + tid;
        s_rp[tid] = rp[r < n ? r : n];
    }
    for (int i = tid; i < 16 * 132; i += 256) (&s_acc[0][0])[i] = 0.f;
    __syncthreads();

    const int sg = tid >> 4;          // 0..15
    const int c8 = (tid & 15) * 8;    // feature base (8 fp16 / 8 fp32 per lane)
    const int te0 = s_rp[0], te1 = s_rp[16];
    const int chunk = (te1 - te0 + 15) >> 4;
    int e = te0 + sg * chunk;
    const int e1 = min(e + chunk, te1);

    union U8 { uint4 u; _Float16 h[8]; };
    if (e < e1) {
        int cur = 0;
        while (s_rp[cur + 1] <= e) cur++;   // starting row of this chunk
        int rp_next = s_rp[cur + 1];
        float a[8] = {0.f, 0.f, 0.f, 0.f, 0.f, 0.f, 0.f, 0.f};
        for (; e + 8 <= e1; e += 8) {
            int c[8]; float v[8]; U8 g[8];
#pragma unroll
            for (int j = 0; j < 8; j++) { c[j] = col[e + j]; v[j] = vals[e + j]; }
#pragma unroll
            for (int j = 0; j < 8; j++) g[j].u = *(const uint4*)&yprev[c[j] * D + c8];
#pragma unroll
            for (int j = 0; j < 8; j++) {
                while (e + j >= rp_next) {   // row boundary: flush partial
#pragma unroll
                    for (int k = 0; k < 8; k++) {
                        atomicAdd(&s_acc[cur][c8 + k], a[k]); a[k] = 0.f;
                    }
                    cur++; rp_next = s_rp[cur + 1];
                }
#pragma unroll
                for (int k = 0; k < 8; k++) a[k] += v[j] * (float)g[j].h[k];
            }
        }
        for (; e < e1; e++) {
            U8 g; g.u = *(const uint4*)&yprev[col[e] * D + c8];
            float v = vals[e];
            while (e >= rp_next) {
#pragma unroll
                for (int k = 0; k < 8; k++) {
                    atomicAdd(&s_acc[cur][c8 + k], a[k]); a[k] = 0.f;
                }
                cur++; rp_next = s_rp[cur + 1];
            }
#pragma unroll
            for (int k = 0; k < 8; k++) a[k] += v * (float)g.h[k];
        }
#pragma unroll
        for (int k = 0; k < 8; k++) atomicAdd(&s_acc[cur][c8 + k], a[k]);
    }
    __syncthreads();

    // MFMA phase: relu + cvt fp32->fp16 while building A-fragments.
    const int w = tid >> 6, lane = tid & 63;
    const int quad = lane >> 4, l16 = lane & 15;
    f32x4 acc[2] = {};
#pragma unroll
    for (int kt = 0; kt < 4; kt++) {
        const float* src = &s_acc[l16][kt * 32 + quad * 8];
        f16x8 af;
#pragma unroll
        for (int k = 0; k < 8; k++) af[k] = (_Float16)fmaxf(src[k], 0.f);
#pragma unroll
        for (int c = 0; c < 2; c++) {
            const int ct = w * 2 + c;
            f16x8 bf = *(const f16x8*)&wwB_l[((kt * D + ct * 16 + l16) << 5) + quad * 8];
            acc[c] = __builtin_amdgcn_mfma_f32_16x16x32_f16(af, bf, acc[c], 0, 0, 0);
        }
    }
#pragma unroll
    for (int c = 0; c < 2; c++) {
        const int ct = w * 2 + c;
#pragma unroll
        for (int rg = 0; rg < 4; rg++) {
            int row = row0 + quad * 4 + rg;
            if (row < n) ynext[row * D + ct * 16 + l16] = (_Float16)acc[c][rg];
        }
    }
}

// gather-accumulate core (single row per subgroup), for the final spmm
static __device__ __forceinline__ void gather_row(float (&a)[8],
                                                  const _Float16* __restrict__ y,
                                                  const int* __restrict__ col,
                                                  const float* __restrict__ vals,
                                                  int e, int e1, int c8) {
    union U8 { uint4 u; _Float16 h[8]; };
    for (; e + 8 <= e1; e += 8) {
        int c[8]; float v[8]; U8 g[8];
#pragma unroll
        for (int j = 0; j < 8; j++) { c[j] = col[e + j]; v[j] = vals[e + j]; }
#pragma unroll
        for (int j = 0; j < 8; j++) g[j].u = *(const uint4*)&y[c[j] * D + c8];
#pragma unroll
        for (int j = 0; j < 8; j++)
#pragma unroll
            for (int k = 0; k < 8; k++) a[k] += v[j] * (float)g[j].h[k];
    }
    for (; e + 4 <= e1; e += 4) {
        int c[4]; float v[4]; U8 g[4];
#pragma unroll
        for (int j = 0; j < 4; j++) { c[j] = col[e + j]; v[j] = vals[e + j]; }
#pragma unroll
        for (int j = 0; j < 4; j++) g[j].u = *(const uint4*)&y[c[j] * D + c8];
#pragma unroll
        for (int j = 0; j < 4; j++)
#pragma unroll
            for (int k = 0; k < 8; k++) a[k] += v[j] * (float)g[j].h[k];
    }
    for (; e < e1; e++) {
        U8 g; g.u = *(const uint4*)&y[col[e] * D + c8];
        float v = vals[e];
#pragma unroll
        for (int k = 0; k < 8; k++) a[k] += v * (float)g.h[k];
    }
}

// Final: out = adj * Y3, fp32 out. No barrier -> imbalance hidden by backfill.
__global__ __launch_bounds__(256, 8)
void spmm_f32(const _Float16* __restrict__ y, const int* __restrict__ rp,
              const int* __restrict__ col, const float* __restrict__ vals,
              float* __restrict__ out, int n) {
    const int tid = threadIdx.x;
    const int r = blockIdx.x * 16 + (tid >> 4);
    const int c8 = (tid & 15) * 8;
    if (r >= n) return;
    float a[8] = {0.f, 0.f, 0.f, 0.f, 0.f, 0.f, 0.f, 0.f};
    gather_row(a, y, col, vals, rp[r], rp[r + 1], c8);
    *(float4*)&out[r * D + c8]     = make_float4(a[0], a[1], a[2], a[3]);
    *(float4*)&out[r * D + c8 + 4] = make_float4(a[4], a[5], a[6], a[7]);
}

extern "C" void kernel_launch(void* const* d_in, const int* in_sizes, int n_in,
                              void* d_out, int out_size, void* d_ws, size_t ws_size,
                              hipStream_t stream) {
    const int*   edge_row  = (const int*)d_in[0];
    const int*   edge_col  = (const int*)d_in[1];
    const float* edge_vals = (const float*)d_in[2];
    const float* x         = (const float*)d_in[3];
    const float* sp        = (const float*)d_in[4];
    const float* lw        = (const float*)d_in[5];
    float* out = (float*)d_out;

    const int E_ = in_sizes[0];
    const int N_ = in_sizes[3] / D;

    // Workspace: row_ptr | wwB (fp16 frag layout) | bufA (N*D f16) | bufB
    char* ws = (char*)d_ws;
    int* row_ptr = (int*)ws;
    size_t off = (((size_t)(N_ + 1) * sizeof(int)) + 255) & ~(size_t)255;
    _Float16* wwB = (_Float16*)(ws + off);
    off += (size_t)L * 4 * D * 32 * sizeof(_Float16);
    off = (off + 255) & ~(size_t)255;
    _Float16* bufA = (_Float16*)(ws + off);
    off += (size_t)N_ * D * sizeof(_Float16);
    _Float16* bufB = (_Float16*)(ws + off);

    build_row_ptr<<<(N_ + 1 + 255) / 256, 256, 0, stream>>>(edge_row, row_ptr, N_, E_);
    build_ww<<<(L * D * D + 255) / 256, 256, 0, stream>>>(sp, lw, wwB);

    const int sblk = (N_ + 15) / 16;
    const int WWL = 4 * D * 32;   // per-layer wwB stride

    // Y1 = x*W0 ; Y2 = relu(adj*Y1)*W1 ; Y3 = relu(adj*Y2)*W2 ; out = adj*Y3
    gemm_x32<<<sblk, 256, 0, stream>>>(x, wwB, bufA, N_);
    fused_layer<<<sblk, 256, 0, stream>>>(bufA, row_ptr, edge_col, edge_vals,
                                          wwB + WWL,     bufB, N_);
    fused_layer<<<sblk, 256, 0, stream>>>(bufB, row_ptr, edge_col, edge_vals,
                                          wwB + 2 * WWL, bufA, N_);
    spmm_f32<<<sblk, 256, 0, stream>>>(bufA, row_ptr, edge_col, edge_vals, out, N_);
}